// Round 1
// baseline (534.440 us; speedup 1.0000x reference)
//
#include <hip/hip_runtime.h>

// ---------------------------------------------------------------------------
// MMoE: B=8192, D_IN=1024, E=8, T=4, H1=1024, H2=512, H3=256
// Strategy: bf16 MFMA GEMMs (m97 structure: 128x128 tile, 16x16x32 mfma,
// global_load_lds width=16), fp32 gating, fused bias+relu epilogue.
// ---------------------------------------------------------------------------

#define B_ROWS 8192
#define D_IN   1024
#define NEXP   8
#define NTASK  4
#define H1     1024
#define H2     512
#define H3     256

typedef __attribute__((ext_vector_type(8))) short bf16x8;
typedef __attribute__((ext_vector_type(4))) float f32x4;

__device__ __forceinline__ unsigned short f2bf(float f) {
    union { float f; unsigned int u; } x; x.f = f;
    unsigned int r = x.u + 0x7fffu + ((x.u >> 16) & 1u);  // RNE
    return (unsigned short)(r >> 16);
}
__device__ __forceinline__ float bf2f(unsigned short u) {
    union { unsigned int u; float f; } x; x.u = ((unsigned int)u) << 16;
    return x.f;
}

__device__ __forceinline__ void gload_lds16(const void* gptr, void* lptr) {
    __builtin_amdgcn_global_load_lds(
        (__attribute__((address_space(1))) void*)gptr,
        (__attribute__((address_space(3))) void*)lptr,
        16, 0, 0);
}

// ---------------------------------------------------------------------------
// x fp32 -> bf16, 4 elements/thread
// ---------------------------------------------------------------------------
struct __align__(8) us4 { unsigned short x, y, z, w; };

__global__ void convert_x_kernel(const float* __restrict__ x,
                                 unsigned short* __restrict__ xb) {
    int i = blockIdx.x * blockDim.x + threadIdx.x;
    float4 v = ((const float4*)x)[i];
    us4 o;
    o.x = f2bf(v.x); o.y = f2bf(v.y); o.z = f2bf(v.z); o.w = f2bf(v.w);
    ((us4*)xb)[i] = o;
}

// ---------------------------------------------------------------------------
// W [E][K][N] fp32 -> Wt [E][N][K] bf16 (32x32 LDS tile transpose)
// ---------------------------------------------------------------------------
__global__ void transpose_convert_kernel(const float* __restrict__ W,
                                         unsigned short* __restrict__ Wt,
                                         int K, int N) {
    __shared__ float tile[32][33];
    const int e = blockIdx.z;
    const float* We = W + (size_t)e * K * N;
    unsigned short* Wte = Wt + (size_t)e * K * N;
    const int k0 = blockIdx.x * 32, n0 = blockIdx.y * 32;
    const int tx = threadIdx.x, ty = threadIdx.y;  // (32, 8)
#pragma unroll
    for (int i = 0; i < 4; ++i)
        tile[ty + i * 8][tx] = We[(size_t)(k0 + ty + i * 8) * N + n0 + tx];
    __syncthreads();
#pragma unroll
    for (int i = 0; i < 4; ++i)
        Wte[(size_t)(n0 + ty + i * 8) * K + k0 + tx] = f2bf(tile[tx][ty + i * 8]);
}

// ---------------------------------------------------------------------------
// GEMM: C[e] = relu(A[e] @ Bt[e]^T + bias[e]) ; all bf16, acc fp32
// A: [M,K] rm (per-expert stride Aes elems), Bt: [N,K] rm, C: [M,N] rm bf16
// block = 256 (4 waves, 2x2), tile 128x128, BK=32
// ---------------------------------------------------------------------------
__global__ __launch_bounds__(256) void gemm_bias_relu_kernel(
    const unsigned short* __restrict__ A, long long Aes,
    const unsigned short* __restrict__ Bt, long long Bes,
    const float* __restrict__ bias, long long bias_es,
    unsigned short* __restrict__ C, long long Ces,
    int M, int N, int K) {
    __shared__ __align__(16) unsigned short sA[128 * 32];
    __shared__ __align__(16) unsigned short sB[128 * 32];

    const int tid  = threadIdx.x;
    const int lane = tid & 63;
    const int w    = tid >> 6;       // wave 0..3
    const int wr   = w >> 1, wc = w & 1;
    const int quad = lane >> 4, l15 = lane & 15;
    const int sr   = lane >> 2;      // staging row-in-chunk 0..15
    const int sc   = lane & 3;       // staging 16B-column 0..3

    const int e  = blockIdx.z;
    const int m0 = blockIdx.x * 128;
    const int n0 = blockIdx.y * 128;

    A    += (size_t)e * Aes;
    Bt   += (size_t)e * Bes;
    bias += (size_t)e * bias_es;
    C    += (size_t)e * Ces;

    f32x4 acc[4][4] = {};

    for (int k0 = 0; k0 < K; k0 += 32) {
        // stage A tile [128][32]: wave w covers rows [w*32, w*32+32)
#pragma unroll
        for (int q = 0; q < 2; ++q) {
            const int row = w * 32 + q * 16 + sr;
            gload_lds16(A + (size_t)(m0 + row) * K + k0 + sc * 8,
                        &sA[row * 32 + sc * 8]);
        }
        // stage Bt tile [128][32]
#pragma unroll
        for (int q = 0; q < 2; ++q) {
            const int row = w * 32 + q * 16 + sr;
            gload_lds16(Bt + (size_t)(n0 + row) * K + k0 + sc * 8,
                        &sB[row * 32 + sc * 8]);
        }
        __syncthreads();

        bf16x8 af[4], bfv[4];
#pragma unroll
        for (int i = 0; i < 4; ++i)
            af[i] = *(const bf16x8*)&sA[(wr * 64 + i * 16 + l15) * 32 + quad * 8];
#pragma unroll
        for (int j = 0; j < 4; ++j)
            bfv[j] = *(const bf16x8*)&sB[(wc * 64 + j * 16 + l15) * 32 + quad * 8];
#pragma unroll
        for (int i = 0; i < 4; ++i)
#pragma unroll
            for (int j = 0; j < 4; ++j)
                acc[i][j] = __builtin_amdgcn_mfma_f32_16x16x32_bf16(
                    af[i], bfv[j], acc[i][j], 0, 0, 0);
        __syncthreads();
    }

    // epilogue: C/D layout col=lane&15, row=quad*4+reg
#pragma unroll
    for (int j = 0; j < 4; ++j) {
        const int col = n0 + wc * 64 + j * 16 + l15;
        const float bv = bias[col];
#pragma unroll
        for (int i = 0; i < 4; ++i) {
#pragma unroll
            for (int r = 0; r < 4; ++r) {
                const int row = m0 + wr * 64 + i * 16 + quad * 4 + r;
                float v = acc[i][j][r] + bv;
                v = v > 0.f ? v : 0.f;
                C[(size_t)row * N + col] = f2bf(v);
            }
        }
    }
}

// ---------------------------------------------------------------------------
// gates: logits = x @ gate_w  [B, 32]; softmax over e within each task group
// block 256 = 8 rows x 32 outputs; output gates[b][t*8+e]
// ---------------------------------------------------------------------------
__global__ void gates_kernel(const float* __restrict__ x,
                             const float* __restrict__ gw,
                             float* __restrict__ gates) {
    const int tid = threadIdx.x;
    const int o = tid & 31;          // t*8 + e
    const int r = tid >> 5;          // 0..7
    const int b = blockIdx.x * 8 + r;
    const float* xr = x + (size_t)b * D_IN;
    float acc = 0.f;
    for (int k = 0; k < D_IN; k += 4) {
        float4 xv = *(const float4*)&xr[k];
        acc += xv.x * gw[(k + 0) * 32 + o];
        acc += xv.y * gw[(k + 1) * 32 + o];
        acc += xv.z * gw[(k + 2) * 32 + o];
        acc += xv.w * gw[(k + 3) * 32 + o];
    }
    // softmax over the 8 experts (lanes o = t*8 + e, e in low 3 bits)
    float m = acc;
    m = fmaxf(m, __shfl_xor(m, 1));
    m = fmaxf(m, __shfl_xor(m, 2));
    m = fmaxf(m, __shfl_xor(m, 4));
    float ex = __expf(acc - m);
    float s = ex;
    s += __shfl_xor(s, 1);
    s += __shfl_xor(s, 2);
    s += __shfl_xor(s, 4);
    gates[(size_t)b * 32 + o] = ex / s;
}

// ---------------------------------------------------------------------------
// combine: out[t][b][d] = sum_e h3[e][b][d] * g[b][t*8+e]
// one block per b, 256 threads = d
// ---------------------------------------------------------------------------
__global__ void combine_kernel(const unsigned short* __restrict__ h3,
                               const float* __restrict__ gates,
                               float* __restrict__ out) {
    __shared__ float g[32];
    const int b = blockIdx.x;
    const int d = threadIdx.x;
    if (d < 32) g[d] = gates[(size_t)b * 32 + d];
    __syncthreads();
    float acc[NTASK] = {0.f, 0.f, 0.f, 0.f};
#pragma unroll
    for (int e = 0; e < NEXP; ++e) {
        const float h = bf2f(h3[((size_t)e * B_ROWS + b) * H3 + d]);
#pragma unroll
        for (int t = 0; t < NTASK; ++t) acc[t] += h * g[t * 8 + e];
    }
#pragma unroll
    for (int t = 0; t < NTASK; ++t)
        out[((size_t)t * B_ROWS + b) * H3 + d] = acc[t];
}

// ---------------------------------------------------------------------------
// workspace layout (bytes)
// ---------------------------------------------------------------------------
#define OFF_XBF 0u                          // 8192*1024*2      = 16,777,216
#define OFF_W1T 16777216u                   // 8*1024*1024*2    = 16,777,216
#define OFF_W2T 33554432u                   // 8*512*1024*2     =  8,388,608
#define OFF_W3T 41943040u                   // 8*256*512*2      =  2,097,152
#define OFF_G   44040192u                   // 8192*32*4        =  1,048,576
#define OFF_H1  45088768u                   // 8*8192*1024*2    = 134,217,728
#define OFF_H2  179306496u                  // 8*8192*512*2     = 67,108,864
#define OFF_H3  45088768u                   // aliases h1 (h1 dead after L2)
// total required: 246,415,360 bytes

extern "C" void kernel_launch(void* const* d_in, const int* in_sizes, int n_in,
                              void* d_out, int out_size, void* d_ws, size_t ws_size,
                              hipStream_t stream) {
    const float* x  = (const float*)d_in[0];
    const float* W1 = (const float*)d_in[1];
    const float* b1 = (const float*)d_in[2];
    const float* W2 = (const float*)d_in[3];
    const float* b2 = (const float*)d_in[4];
    const float* W3 = (const float*)d_in[5];
    const float* b3 = (const float*)d_in[6];
    const float* gw = (const float*)d_in[7];
    float* out = (float*)d_out;
    char* ws = (char*)d_ws;

    unsigned short* xbf = (unsigned short*)(ws + OFF_XBF);
    unsigned short* w1t = (unsigned short*)(ws + OFF_W1T);
    unsigned short* w2t = (unsigned short*)(ws + OFF_W2T);
    unsigned short* w3t = (unsigned short*)(ws + OFF_W3T);
    float*          gts = (float*)(ws + OFF_G);
    unsigned short* h1  = (unsigned short*)(ws + OFF_H1);
    unsigned short* h2  = (unsigned short*)(ws + OFF_H2);
    unsigned short* h3  = (unsigned short*)(ws + OFF_H3);

    // input conversions
    convert_x_kernel<<<dim3((B_ROWS * D_IN) / 4 / 256), dim3(256), 0, stream>>>(x, xbf);
    transpose_convert_kernel<<<dim3(D_IN / 32, H1 / 32, NEXP), dim3(32, 8), 0, stream>>>(W1, w1t, D_IN, H1);
    transpose_convert_kernel<<<dim3(H1 / 32, H2 / 32, NEXP), dim3(32, 8), 0, stream>>>(W2, w2t, H1, H2);
    transpose_convert_kernel<<<dim3(H2 / 32, H3 / 32, NEXP), dim3(32, 8), 0, stream>>>(W3, w3t, H2, H3);

    // gates (fp32, independent of expert path)
    gates_kernel<<<dim3(B_ROWS / 8), dim3(256), 0, stream>>>(x, gw, gts);

    // expert MLP layers
    gemm_bias_relu_kernel<<<dim3(B_ROWS / 128, H1 / 128, NEXP), dim3(256), 0, stream>>>(
        xbf, 0LL,
        w1t, (long long)H1 * D_IN,
        b1, (long long)H1,
        h1, (long long)B_ROWS * H1,
        B_ROWS, H1, D_IN);
    gemm_bias_relu_kernel<<<dim3(B_ROWS / 128, H2 / 128, NEXP), dim3(256), 0, stream>>>(
        h1, (long long)B_ROWS * H1,
        w2t, (long long)H2 * H1,
        b2, (long long)H2,
        h2, (long long)B_ROWS * H2,
        B_ROWS, H2, H1);
    gemm_bias_relu_kernel<<<dim3(B_ROWS / 128, H3 / 128, NEXP), dim3(256), 0, stream>>>(
        h2, (long long)B_ROWS * H2,
        w3t, (long long)H3 * H2,
        b3, (long long)H3,
        h3, (long long)B_ROWS * H3,
        B_ROWS, H3, H2);

    // gated combine
    combine_kernel<<<dim3(B_ROWS), dim3(256), 0, stream>>>(h3, gts, out);
}

// Round 2
// 501.788 us; speedup vs baseline: 1.0651x; 1.0651x over previous
//
#include <hip/hip_runtime.h>

// ---------------------------------------------------------------------------
// MMoE: B=8192, D_IN=1024, E=8, T=4, H1=1024, H2=512, H3=256
// bf16 MFMA GEMMs: 128x128 tile, BK=64, 16x16x32 mfma, global_load_lds w=16,
// XOR-swizzled LDS to kill bank conflicts. fp32 gating, fused bias+relu.
// ---------------------------------------------------------------------------

#define B_ROWS 8192
#define D_IN   1024
#define NEXP   8
#define NTASK  4
#define H1     1024
#define H2     512
#define H3     256

typedef __attribute__((ext_vector_type(8))) short bf16x8;
typedef __attribute__((ext_vector_type(4))) float f32x4;

__device__ __forceinline__ unsigned short f2bf(float f) {
    union { float f; unsigned int u; } x; x.f = f;
    unsigned int r = x.u + 0x7fffu + ((x.u >> 16) & 1u);  // RNE
    return (unsigned short)(r >> 16);
}
__device__ __forceinline__ float bf2f(unsigned short u) {
    union { unsigned int u; float f; } x; x.u = ((unsigned int)u) << 16;
    return x.f;
}

__device__ __forceinline__ void gload_lds16(const void* gptr, void* lptr) {
    __builtin_amdgcn_global_load_lds(
        (__attribute__((address_space(1))) void*)gptr,
        (__attribute__((address_space(3))) void*)lptr,
        16, 0, 0);
}

// ---------------------------------------------------------------------------
// x fp32 -> bf16, 4 elements/thread
// ---------------------------------------------------------------------------
struct __align__(8) us4 { unsigned short x, y, z, w; };

__global__ void convert_x_kernel(const float* __restrict__ x,
                                 unsigned short* __restrict__ xb) {
    int i = blockIdx.x * blockDim.x + threadIdx.x;
    float4 v = ((const float4*)x)[i];
    us4 o;
    o.x = f2bf(v.x); o.y = f2bf(v.y); o.z = f2bf(v.z); o.w = f2bf(v.w);
    ((us4*)xb)[i] = o;
}

// ---------------------------------------------------------------------------
// W [E][K][N] fp32 -> Wt [E][N][K] bf16 (32x32 LDS tile transpose)
// ---------------------------------------------------------------------------
__global__ void transpose_convert_kernel(const float* __restrict__ W,
                                         unsigned short* __restrict__ Wt,
                                         int K, int N) {
    __shared__ float tile[32][33];
    const int e = blockIdx.z;
    const float* We = W + (size_t)e * K * N;
    unsigned short* Wte = Wt + (size_t)e * K * N;
    const int k0 = blockIdx.x * 32, n0 = blockIdx.y * 32;
    const int tx = threadIdx.x, ty = threadIdx.y;  // (32, 8)
#pragma unroll
    for (int i = 0; i < 4; ++i)
        tile[ty + i * 8][tx] = We[(size_t)(k0 + ty + i * 8) * N + n0 + tx];
    __syncthreads();
#pragma unroll
    for (int i = 0; i < 4; ++i)
        Wte[(size_t)(n0 + ty + i * 8) * K + k0 + tx] = f2bf(tile[tx][ty + i * 8]);
}

// ---------------------------------------------------------------------------
// GEMM: C[e] = relu(A[e] @ Bt[e]^T + bias[e]) ; all bf16, acc fp32
// A: [M,K] rm (per-expert stride Aes elems), Bt: [N,K] rm, C: [M,N] rm bf16
// block = 256 (4 waves, 2x2), tile 128x128, BK=64.
// LDS rows are 8 chunks of 16B; chunk c of row r holds global chunk c^(r&7)
// (XOR swizzle) so ds_read_b128 fragment reads spread across all 32 banks.
// K must be a multiple of 64.
// ---------------------------------------------------------------------------
__global__ __launch_bounds__(256) void gemm_bias_relu_kernel(
    const unsigned short* __restrict__ A, long long Aes,
    const unsigned short* __restrict__ Bt, long long Bes,
    const float* __restrict__ bias, long long bias_es,
    unsigned short* __restrict__ C, long long Ces,
    int M, int N, int K) {
    __shared__ __align__(16) unsigned short sA[128 * 64];
    __shared__ __align__(16) unsigned short sB[128 * 64];

    const int tid  = threadIdx.x;
    const int lane = tid & 63;
    const int w    = tid >> 6;       // wave 0..3
    const int wr   = w >> 1, wc = w & 1;
    const int quad = lane >> 4, l15 = lane & 15;
    const int r8   = lane >> 3;      // staging row-in-octet 0..7
    const int c8   = lane & 7;       // staging 16B-chunk 0..7
    const int gchunk = c8 ^ r8;      // XOR-swizzled global chunk to fetch

    const int e  = blockIdx.z;
    const int m0 = blockIdx.x * 128;
    const int n0 = blockIdx.y * 128;

    A    += (size_t)e * Aes;
    Bt   += (size_t)e * Bes;
    bias += (size_t)e * bias_es;
    C    += (size_t)e * Ces;

    f32x4 acc[4][4] = {};

    const int swz = (l15 & 7);       // read-side XOR (row&7 of fragment rows)

    for (int k0 = 0; k0 < K; k0 += 64) {
        // stage A tile [128][64]: wave w covers rows [w*32, w*32+32)
        // each gload16 issue covers 8 rows (8 rows x 128B = 1KB = 64 lanes x 16B)
#pragma unroll
        for (int q = 0; q < 4; ++q) {
            const int row = w * 32 + q * 8 + r8;
            gload_lds16(A + (size_t)(m0 + row) * K + k0 + gchunk * 8,
                        &sA[row * 64 + c8 * 8]);
        }
#pragma unroll
        for (int q = 0; q < 4; ++q) {
            const int row = w * 32 + q * 8 + r8;
            gload_lds16(Bt + (size_t)(n0 + row) * K + k0 + gchunk * 8,
                        &sB[row * 64 + c8 * 8]);
        }
        __syncthreads();

#pragma unroll
        for (int s = 0; s < 2; ++s) {
            const int cs = ((s * 4 + quad) ^ swz) * 8;  // swizzled k-chunk
            bf16x8 af[4], bfv[4];
#pragma unroll
            for (int i = 0; i < 4; ++i)
                af[i] = *(const bf16x8*)&sA[(wr * 64 + i * 16 + l15) * 64 + cs];
#pragma unroll
            for (int j = 0; j < 4; ++j)
                bfv[j] = *(const bf16x8*)&sB[(wc * 64 + j * 16 + l15) * 64 + cs];
#pragma unroll
            for (int i = 0; i < 4; ++i)
#pragma unroll
                for (int j = 0; j < 4; ++j)
                    acc[i][j] = __builtin_amdgcn_mfma_f32_16x16x32_bf16(
                        af[i], bfv[j], acc[i][j], 0, 0, 0);
        }
        __syncthreads();
    }

    // epilogue: C/D layout col=lane&15, row=quad*4+reg
#pragma unroll
    for (int j = 0; j < 4; ++j) {
        const int col = n0 + wc * 64 + j * 16 + l15;
        const float bv = bias[col];
#pragma unroll
        for (int i = 0; i < 4; ++i) {
#pragma unroll
            for (int r = 0; r < 4; ++r) {
                const int row = m0 + wr * 64 + i * 16 + quad * 4 + r;
                float v = acc[i][j][r] + bv;
                v = v > 0.f ? v : 0.f;
                C[(size_t)row * N + col] = f2bf(v);
            }
        }
    }
}

// ---------------------------------------------------------------------------
// gates: logits = x @ gate_w  [B, 32]; softmax over e within each task group
// block 256 = 8 rows x 32 outputs; output gates[b][t*8+e]
// ---------------------------------------------------------------------------
__global__ void gates_kernel(const float* __restrict__ x,
                             const float* __restrict__ gw,
                             float* __restrict__ gates) {
    const int tid = threadIdx.x;
    const int o = tid & 31;          // t*8 + e
    const int r = tid >> 5;          // 0..7
    const int b = blockIdx.x * 8 + r;
    const float* xr = x + (size_t)b * D_IN;
    float acc = 0.f;
    for (int k = 0; k < D_IN; k += 4) {
        float4 xv = *(const float4*)&xr[k];
        acc += xv.x * gw[(k + 0) * 32 + o];
        acc += xv.y * gw[(k + 1) * 32 + o];
        acc += xv.z * gw[(k + 2) * 32 + o];
        acc += xv.w * gw[(k + 3) * 32 + o];
    }
    // softmax over the 8 experts (lanes o = t*8 + e, e in low 3 bits)
    float m = acc;
    m = fmaxf(m, __shfl_xor(m, 1));
    m = fmaxf(m, __shfl_xor(m, 2));
    m = fmaxf(m, __shfl_xor(m, 4));
    float ex = __expf(acc - m);
    float s = ex;
    s += __shfl_xor(s, 1);
    s += __shfl_xor(s, 2);
    s += __shfl_xor(s, 4);
    gates[(size_t)b * 32 + o] = ex / s;
}

// ---------------------------------------------------------------------------
// combine: out[t][b][d] = sum_e h3[e][b][d] * g[b][t*8+e]
// one block per b, 256 threads = d
// ---------------------------------------------------------------------------
__global__ void combine_kernel(const unsigned short* __restrict__ h3,
                               const float* __restrict__ gates,
                               float* __restrict__ out) {
    __shared__ float g[32];
    const int b = blockIdx.x;
    const int d = threadIdx.x;
    if (d < 32) g[d] = gates[(size_t)b * 32 + d];
    __syncthreads();
    float acc[NTASK] = {0.f, 0.f, 0.f, 0.f};
#pragma unroll
    for (int e = 0; e < NEXP; ++e) {
        const float h = bf2f(h3[((size_t)e * B_ROWS + b) * H3 + d]);
#pragma unroll
        for (int t = 0; t < NTASK; ++t) acc[t] += h * g[t * 8 + e];
    }
#pragma unroll
    for (int t = 0; t < NTASK; ++t)
        out[((size_t)t * B_ROWS + b) * H3 + d] = acc[t];
}

// ---------------------------------------------------------------------------
// workspace layout (bytes)
// ---------------------------------------------------------------------------
#define OFF_XBF 0u                          // 8192*1024*2      = 16,777,216
#define OFF_W1T 16777216u                   // 8*1024*1024*2    = 16,777,216
#define OFF_W2T 33554432u                   // 8*512*1024*2     =  8,388,608
#define OFF_W3T 41943040u                   // 8*256*512*2      =  2,097,152
#define OFF_G   44040192u                   // 8192*32*4        =  1,048,576
#define OFF_H1  45088768u                   // 8*8192*1024*2    = 134,217,728
#define OFF_H2  179306496u                  // 8*8192*512*2     = 67,108,864
#define OFF_H3  45088768u                   // aliases h1 (h1 dead after L2)
// total required: 246,415,360 bytes

extern "C" void kernel_launch(void* const* d_in, const int* in_sizes, int n_in,
                              void* d_out, int out_size, void* d_ws, size_t ws_size,
                              hipStream_t stream) {
    const float* x  = (const float*)d_in[0];
    const float* W1 = (const float*)d_in[1];
    const float* b1 = (const float*)d_in[2];
    const float* W2 = (const float*)d_in[3];
    const float* b2 = (const float*)d_in[4];
    const float* W3 = (const float*)d_in[5];
    const float* b3 = (const float*)d_in[6];
    const float* gw = (const float*)d_in[7];
    float* out = (float*)d_out;
    char* ws = (char*)d_ws;

    unsigned short* xbf = (unsigned short*)(ws + OFF_XBF);
    unsigned short* w1t = (unsigned short*)(ws + OFF_W1T);
    unsigned short* w2t = (unsigned short*)(ws + OFF_W2T);
    unsigned short* w3t = (unsigned short*)(ws + OFF_W3T);
    float*          gts = (float*)(ws + OFF_G);
    unsigned short* h1  = (unsigned short*)(ws + OFF_H1);
    unsigned short* h2  = (unsigned short*)(ws + OFF_H2);
    unsigned short* h3  = (unsigned short*)(ws + OFF_H3);

    // input conversions
    convert_x_kernel<<<dim3((B_ROWS * D_IN) / 4 / 256), dim3(256), 0, stream>>>(x, xbf);
    transpose_convert_kernel<<<dim3(D_IN / 32, H1 / 32, NEXP), dim3(32, 8), 0, stream>>>(W1, w1t, D_IN, H1);
    transpose_convert_kernel<<<dim3(H1 / 32, H2 / 32, NEXP), dim3(32, 8), 0, stream>>>(W2, w2t, H1, H2);
    transpose_convert_kernel<<<dim3(H2 / 32, H3 / 32, NEXP), dim3(32, 8), 0, stream>>>(W3, w3t, H2, H3);

    // gates (fp32, independent of expert path)
    gates_kernel<<<dim3(B_ROWS / 8), dim3(256), 0, stream>>>(x, gw, gts);

    // expert MLP layers
    gemm_bias_relu_kernel<<<dim3(B_ROWS / 128, H1 / 128, NEXP), dim3(256), 0, stream>>>(
        xbf, 0LL,
        w1t, (long long)H1 * D_IN,
        b1, (long long)H1,
        h1, (long long)B_ROWS * H1,
        B_ROWS, H1, D_IN);
    gemm_bias_relu_kernel<<<dim3(B_ROWS / 128, H2 / 128, NEXP), dim3(256), 0, stream>>>(
        h1, (long long)B_ROWS * H1,
        w2t, (long long)H2 * H1,
        b2, (long long)H2,
        h2, (long long)B_ROWS * H2,
        B_ROWS, H2, H1);
    gemm_bias_relu_kernel<<<dim3(B_ROWS / 128, H3 / 128, NEXP), dim3(256), 0, stream>>>(
        h2, (long long)B_ROWS * H2,
        w3t, (long long)H3 * H2,
        b3, (long long)H3,
        h3, (long long)B_ROWS * H3,
        B_ROWS, H3, H2);

    // gated combine
    combine_kernel<<<dim3(B_ROWS), dim3(256), 0, stream>>>(h3, gts, out);
}

// Round 3
// 455.747 us; speedup vs baseline: 1.1727x; 1.1010x over previous
//
#include <hip/hip_runtime.h>

// ---------------------------------------------------------------------------
// MMoE: B=8192, D_IN=1024, E=8, T=4, H1=1024, H2=512, H3=256
// bf16 MFMA GEMMs: block tile 256x128 (4 waves, wave tile 128x64), BK=64,
// 16x16x32 mfma, global_load_lds w=16, XOR-swizzled LDS (0 bank conflicts).
// Wave tile 128x64 -> 12 ds_read_b128 per 32 MFMAs = 43.7 FLOP/LDS-byte,
// lifting the structural LDS-read bound of the 64x64 (m97) structure.
// fp32 gating, fused bias+relu epilogue.
// ---------------------------------------------------------------------------

#define B_ROWS 8192
#define D_IN   1024
#define NEXP   8
#define NTASK  4
#define H1     1024
#define H2     512
#define H3     256

typedef __attribute__((ext_vector_type(8))) short bf16x8;
typedef __attribute__((ext_vector_type(4))) float f32x4;

__device__ __forceinline__ unsigned short f2bf(float f) {
    union { float f; unsigned int u; } x; x.f = f;
    unsigned int r = x.u + 0x7fffu + ((x.u >> 16) & 1u);  // RNE
    return (unsigned short)(r >> 16);
}
__device__ __forceinline__ float bf2f(unsigned short u) {
    union { unsigned int u; float f; } x; x.u = ((unsigned int)u) << 16;
    return x.f;
}

__device__ __forceinline__ void gload_lds16(const void* gptr, void* lptr) {
    __builtin_amdgcn_global_load_lds(
        (__attribute__((address_space(1))) void*)gptr,
        (__attribute__((address_space(3))) void*)lptr,
        16, 0, 0);
}

// ---------------------------------------------------------------------------
// x fp32 -> bf16, 4 elements/thread
// ---------------------------------------------------------------------------
struct __align__(8) us4 { unsigned short x, y, z, w; };

__global__ void convert_x_kernel(const float* __restrict__ x,
                                 unsigned short* __restrict__ xb) {
    int i = blockIdx.x * blockDim.x + threadIdx.x;
    float4 v = ((const float4*)x)[i];
    us4 o;
    o.x = f2bf(v.x); o.y = f2bf(v.y); o.z = f2bf(v.z); o.w = f2bf(v.w);
    ((us4*)xb)[i] = o;
}

// ---------------------------------------------------------------------------
// W [E][K][N] fp32 -> Wt [E][N][K] bf16 (32x32 LDS tile transpose)
// ---------------------------------------------------------------------------
__global__ void transpose_convert_kernel(const float* __restrict__ W,
                                         unsigned short* __restrict__ Wt,
                                         int K, int N) {
    __shared__ float tile[32][33];
    const int e = blockIdx.z;
    const float* We = W + (size_t)e * K * N;
    unsigned short* Wte = Wt + (size_t)e * K * N;
    const int k0 = blockIdx.x * 32, n0 = blockIdx.y * 32;
    const int tx = threadIdx.x, ty = threadIdx.y;  // (32, 8)
#pragma unroll
    for (int i = 0; i < 4; ++i)
        tile[ty + i * 8][tx] = We[(size_t)(k0 + ty + i * 8) * N + n0 + tx];
    __syncthreads();
#pragma unroll
    for (int i = 0; i < 4; ++i)
        Wte[(size_t)(n0 + ty + i * 8) * K + k0 + tx] = f2bf(tile[tx][ty + i * 8]);
}

// ---------------------------------------------------------------------------
// GEMM: C[e] = relu(A[e] @ Bt[e]^T + bias[e]) ; all bf16, acc fp32
// A: [M,K] rm (per-expert stride Aes elems), Bt: [N,K] rm, C: [M,N] rm bf16
// block = 256 (4 waves, 2x2), block tile 256x128 (M x N), wave tile 128x64,
// BK=64. LDS rows are 8 chunks of 16B; chunk c of row r holds global chunk
// c^(r&7) (XOR swizzle): ds_read_b128 fragment reads hit all 32 banks.
// M % 256 == 0, N % 128 == 0, K % 64 == 0.
// ---------------------------------------------------------------------------
__global__ __launch_bounds__(256, 2) void gemm_bias_relu_kernel(
    const unsigned short* __restrict__ A, long long Aes,
    const unsigned short* __restrict__ Bt, long long Bes,
    const float* __restrict__ bias, long long bias_es,
    unsigned short* __restrict__ C, long long Ces,
    int M, int N, int K) {
    __shared__ __align__(16) unsigned short sA[256 * 64];
    __shared__ __align__(16) unsigned short sB[128 * 64];

    const int tid  = threadIdx.x;
    const int lane = tid & 63;
    const int w    = tid >> 6;       // wave 0..3
    const int wr   = w >> 1, wc = w & 1;
    const int quad = lane >> 4, l15 = lane & 15;
    const int r8   = lane >> 3;      // staging row-in-octet 0..7
    const int c8   = lane & 7;       // staging 16B-chunk 0..7
    const int gchunk = c8 ^ r8;      // XOR-swizzled global chunk to fetch

    const int e  = blockIdx.z;
    const int m0 = blockIdx.x * 256;
    const int n0 = blockIdx.y * 128;

    A    += (size_t)e * Aes;
    Bt   += (size_t)e * Bes;
    bias += (size_t)e * bias_es;
    C    += (size_t)e * Ces;

    f32x4 acc[8][4] = {};

    const int swz = (l15 & 7);       // read-side XOR (row&7 of fragment rows)

    for (int k0 = 0; k0 < K; k0 += 64) {
        // stage A tile [256][64]: wave w covers rows [w*64, w*64+64)
#pragma unroll
        for (int q = 0; q < 8; ++q) {
            const int row = w * 64 + q * 8 + r8;
            gload_lds16(A + (size_t)(m0 + row) * K + k0 + gchunk * 8,
                        &sA[row * 64 + c8 * 8]);
        }
        // stage B tile [128][64]: wave w covers rows [w*32, w*32+32)
#pragma unroll
        for (int q = 0; q < 4; ++q) {
            const int row = w * 32 + q * 8 + r8;
            gload_lds16(Bt + (size_t)(n0 + row) * K + k0 + gchunk * 8,
                        &sB[row * 64 + c8 * 8]);
        }
        __syncthreads();

#pragma unroll
        for (int s = 0; s < 2; ++s) {
            const int cs = ((s * 4 + quad) ^ swz) * 8;  // swizzled k-chunk
            bf16x8 af[8], bfv[4];
#pragma unroll
            for (int j = 0; j < 4; ++j)
                bfv[j] = *(const bf16x8*)&sB[(wc * 64 + j * 16 + l15) * 64 + cs];
#pragma unroll
            for (int i = 0; i < 8; ++i)
                af[i] = *(const bf16x8*)&sA[(wr * 128 + i * 16 + l15) * 64 + cs];
#pragma unroll
            for (int i = 0; i < 8; ++i)
#pragma unroll
                for (int j = 0; j < 4; ++j)
                    acc[i][j] = __builtin_amdgcn_mfma_f32_16x16x32_bf16(
                        af[i], bfv[j], acc[i][j], 0, 0, 0);
        }
        __syncthreads();
    }

    // epilogue: C/D layout col=lane&15, row=quad*4+reg
#pragma unroll
    for (int j = 0; j < 4; ++j) {
        const int col = n0 + wc * 64 + j * 16 + l15;
        const float bv = bias[col];
#pragma unroll
        for (int i = 0; i < 8; ++i) {
#pragma unroll
            for (int r = 0; r < 4; ++r) {
                const int row = m0 + wr * 128 + i * 16 + quad * 4 + r;
                float v = acc[i][j][r] + bv;
                v = v > 0.f ? v : 0.f;
                C[(size_t)row * N + col] = f2bf(v);
            }
        }
    }
}

// ---------------------------------------------------------------------------
// gates: logits = x @ gate_w  [B, 32]; softmax over e within each task group
// block 256 = 8 rows x 32 outputs; output gates[b][t*8+e]
// ---------------------------------------------------------------------------
__global__ void gates_kernel(const float* __restrict__ x,
                             const float* __restrict__ gw,
                             float* __restrict__ gates) {
    const int tid = threadIdx.x;
    const int o = tid & 31;          // t*8 + e
    const int r = tid >> 5;          // 0..7
    const int b = blockIdx.x * 8 + r;
    const float* xr = x + (size_t)b * D_IN;
    float acc = 0.f;
    for (int k = 0; k < D_IN; k += 4) {
        float4 xv = *(const float4*)&xr[k];
        acc += xv.x * gw[(k + 0) * 32 + o];
        acc += xv.y * gw[(k + 1) * 32 + o];
        acc += xv.z * gw[(k + 2) * 32 + o];
        acc += xv.w * gw[(k + 3) * 32 + o];
    }
    // softmax over the 8 experts (lanes o = t*8 + e, e in low 3 bits)
    float m = acc;
    m = fmaxf(m, __shfl_xor(m, 1));
    m = fmaxf(m, __shfl_xor(m, 2));
    m = fmaxf(m, __shfl_xor(m, 4));
    float ex = __expf(acc - m);
    float s = ex;
    s += __shfl_xor(s, 1);
    s += __shfl_xor(s, 2);
    s += __shfl_xor(s, 4);
    gates[(size_t)b * 32 + o] = ex / s;
}

// ---------------------------------------------------------------------------
// combine: out[t][b][d] = sum_e h3[e][b][d] * g[b][t*8+e]
// one block per b, 256 threads = d
// ---------------------------------------------------------------------------
__global__ void combine_kernel(const unsigned short* __restrict__ h3,
                               const float* __restrict__ gates,
                               float* __restrict__ out) {
    __shared__ float g[32];
    const int b = blockIdx.x;
    const int d = threadIdx.x;
    if (d < 32) g[d] = gates[(size_t)b * 32 + d];
    __syncthreads();
    float acc[NTASK] = {0.f, 0.f, 0.f, 0.f};
#pragma unroll
    for (int e = 0; e < NEXP; ++e) {
        const float h = bf2f(h3[((size_t)e * B_ROWS + b) * H3 + d]);
#pragma unroll
        for (int t = 0; t < NTASK; ++t) acc[t] += h * g[t * 8 + e];
    }
#pragma unroll
    for (int t = 0; t < NTASK; ++t)
        out[((size_t)t * B_ROWS + b) * H3 + d] = acc[t];
}

// ---------------------------------------------------------------------------
// workspace layout (bytes)
// ---------------------------------------------------------------------------
#define OFF_XBF 0u                          // 8192*1024*2      = 16,777,216
#define OFF_W1T 16777216u                   // 8*1024*1024*2    = 16,777,216
#define OFF_W2T 33554432u                   // 8*512*1024*2     =  8,388,608
#define OFF_W3T 41943040u                   // 8*256*512*2      =  2,097,152
#define OFF_G   44040192u                   // 8192*32*4        =  1,048,576
#define OFF_H1  45088768u                   // 8*8192*1024*2    = 134,217,728
#define OFF_H2  179306496u                  // 8*8192*512*2     = 67,108,864
#define OFF_H3  45088768u                   // aliases h1 (h1 dead after L2)
// total required: 246,415,360 bytes

extern "C" void kernel_launch(void* const* d_in, const int* in_sizes, int n_in,
                              void* d_out, int out_size, void* d_ws, size_t ws_size,
                              hipStream_t stream) {
    const float* x  = (const float*)d_in[0];
    const float* W1 = (const float*)d_in[1];
    const float* b1 = (const float*)d_in[2];
    const float* W2 = (const float*)d_in[3];
    const float* b2 = (const float*)d_in[4];
    const float* W3 = (const float*)d_in[5];
    const float* b3 = (const float*)d_in[6];
    const float* gw = (const float*)d_in[7];
    float* out = (float*)d_out;
    char* ws = (char*)d_ws;

    unsigned short* xbf = (unsigned short*)(ws + OFF_XBF);
    unsigned short* w1t = (unsigned short*)(ws + OFF_W1T);
    unsigned short* w2t = (unsigned short*)(ws + OFF_W2T);
    unsigned short* w3t = (unsigned short*)(ws + OFF_W3T);
    float*          gts = (float*)(ws + OFF_G);
    unsigned short* h1  = (unsigned short*)(ws + OFF_H1);
    unsigned short* h2  = (unsigned short*)(ws + OFF_H2);
    unsigned short* h3  = (unsigned short*)(ws + OFF_H3);

    // input conversions
    convert_x_kernel<<<dim3((B_ROWS * D_IN) / 4 / 256), dim3(256), 0, stream>>>(x, xbf);
    transpose_convert_kernel<<<dim3(D_IN / 32, H1 / 32, NEXP), dim3(32, 8), 0, stream>>>(W1, w1t, D_IN, H1);
    transpose_convert_kernel<<<dim3(H1 / 32, H2 / 32, NEXP), dim3(32, 8), 0, stream>>>(W2, w2t, H1, H2);
    transpose_convert_kernel<<<dim3(H2 / 32, H3 / 32, NEXP), dim3(32, 8), 0, stream>>>(W3, w3t, H2, H3);

    // gates (fp32, independent of expert path)
    gates_kernel<<<dim3(B_ROWS / 8), dim3(256), 0, stream>>>(x, gw, gts);

    // expert MLP layers
    gemm_bias_relu_kernel<<<dim3(B_ROWS / 256, H1 / 128, NEXP), dim3(256), 0, stream>>>(
        xbf, 0LL,
        w1t, (long long)H1 * D_IN,
        b1, (long long)H1,
        h1, (long long)B_ROWS * H1,
        B_ROWS, H1, D_IN);
    gemm_bias_relu_kernel<<<dim3(B_ROWS / 256, H2 / 128, NEXP), dim3(256), 0, stream>>>(
        h1, (long long)B_ROWS * H1,
        w2t, (long long)H2 * H1,
        b2, (long long)H2,
        h2, (long long)B_ROWS * H2,
        B_ROWS, H2, H1);
    gemm_bias_relu_kernel<<<dim3(B_ROWS / 256, H3 / 128, NEXP), dim3(256), 0, stream>>>(
        h2, (long long)B_ROWS * H2,
        w3t, (long long)H3 * H2,
        b3, (long long)H3,
        h3, (long long)B_ROWS * H3,
        B_ROWS, H3, H2);

    // gated combine
    combine_kernel<<<dim3(B_ROWS), dim3(256), 0, stream>>>(h3, gts, out);
}